// Round 6
// baseline (28349.512 us; speedup 1.0000x reference)
//
#include <hip/hip_runtime.h>
#include <hip/hip_cooperative_groups.h>
#include <math.h>

#define B_   64
#define T_   366
#define IN_  24
#define H1_  1024
#define H2_  2048
#define HM_  2048
#define G3_  (3 * HM_)
#define PEN_ 1024
#define C_   21
#define BT_  (B_ * T_)

#define TC_  61              // T-chunk length (366 = 6*61)
#define NCH  6
#define MC   (B_ * TC_)      // 3904 rows per chunk

typedef unsigned short bf16_t;
typedef __bf16 bf16x8 __attribute__((ext_vector_type(8)));
typedef float  f32x4  __attribute__((ext_vector_type(4)));

__device__ __forceinline__ float bf2f(bf16_t u) {
  return __uint_as_float(((unsigned int)u) << 16);
}
__device__ __forceinline__ bf16_t f2bf(float f) {
  unsigned int x = __float_as_uint(f);
  unsigned int r = (x + 0x7fffu + ((x >> 16) & 1u)) >> 16;
  return (bf16_t)r;
}

struct ushort4_t { bf16_t x, y, z, w; };

// ---------------------------------------------------------------------------
// MFMA bf16 GEMM (unchanged from R5, verified): C = act(A@W^T + b), C bf16.
// ---------------------------------------------------------------------------
#define GBM 128
#define GBN 128
#define GBK 32
#define LDT 40

__global__ __launch_bounds__(256) void gemm_mfma(
    const bf16_t* __restrict__ A, const float* __restrict__ W,
    const float* __restrict__ bias, bf16_t* __restrict__ C,
    int M, int N, int K, int relu)
{
  __shared__ bf16_t Asl[GBM * LDT];
  __shared__ bf16_t Wsl[GBN * LDT];
  const int tid  = threadIdx.x;
  const int m0   = blockIdx.x * GBM;
  const int n0   = blockIdx.y * GBN;
  const int wave = tid >> 6;
  const int lane = tid & 63;
  const int l16  = lane & 15;
  const int quad = lane >> 4;
  const int wm   = (wave & 1) * 64;
  const int wn   = (wave >> 1) * 64;
  const int srow = tid >> 1;
  const int sseg = (tid & 1) << 4;
  const int arow = (m0 + srow < M) ? (m0 + srow) : (M - 1);

  f32x4 acc[4][4];
  #pragma unroll
  for (int i = 0; i < 4; ++i)
    #pragma unroll
    for (int j = 0; j < 4; ++j)
      acc[i][j] = (f32x4){0.f, 0.f, 0.f, 0.f};

  for (int k0 = 0; k0 < K; k0 += GBK) {
    {
      const bf16_t* ga = A + (size_t)arow * K + k0 + sseg;
      const uint4 a0 = *(const uint4*)ga;
      const uint4 a1 = *(const uint4*)(ga + 8);
      *(uint4*)&Asl[srow * LDT + sseg]     = a0;
      *(uint4*)&Asl[srow * LDT + sseg + 8] = a1;
      const float* gw = W + (size_t)(n0 + srow) * K + k0 + sseg;
      const float4 w0 = *(const float4*)gw;
      const float4 w1 = *(const float4*)(gw + 4);
      const float4 w2 = *(const float4*)(gw + 8);
      const float4 w3 = *(const float4*)(gw + 12);
      ushort4_t p0 = {f2bf(w0.x), f2bf(w0.y), f2bf(w0.z), f2bf(w0.w)};
      ushort4_t p1 = {f2bf(w1.x), f2bf(w1.y), f2bf(w1.z), f2bf(w1.w)};
      ushort4_t p2 = {f2bf(w2.x), f2bf(w2.y), f2bf(w2.z), f2bf(w2.w)};
      ushort4_t p3 = {f2bf(w3.x), f2bf(w3.y), f2bf(w3.z), f2bf(w3.w)};
      *(ushort4_t*)&Wsl[srow * LDT + sseg]      = p0;
      *(ushort4_t*)&Wsl[srow * LDT + sseg + 4]  = p1;
      *(ushort4_t*)&Wsl[srow * LDT + sseg + 8]  = p2;
      *(ushort4_t*)&Wsl[srow * LDT + sseg + 12] = p3;
    }
    __syncthreads();
    bf16x8 af[4], bf[4];
    #pragma unroll
    for (int i = 0; i < 4; ++i)
      af[i] = *(const bf16x8*)&Asl[(wm + 16 * i + l16) * LDT + quad * 8];
    #pragma unroll
    for (int j = 0; j < 4; ++j)
      bf[j] = *(const bf16x8*)&Wsl[(wn + 16 * j + l16) * LDT + quad * 8];
    #pragma unroll
    for (int i = 0; i < 4; ++i)
      #pragma unroll
      for (int j = 0; j < 4; ++j)
        acc[i][j] = __builtin_amdgcn_mfma_f32_16x16x32_bf16(af[i], bf[j], acc[i][j], 0, 0, 0);
    __syncthreads();
  }

  #pragma unroll
  for (int j = 0; j < 4; ++j) {
    const int n = n0 + wn + 16 * j + l16;
    const float bn = bias[n];
    #pragma unroll
    for (int i = 0; i < 4; ++i) {
      #pragma unroll
      for (int reg = 0; reg < 4; ++reg) {
        const int m = m0 + wm + 16 * i + quad * 4 + reg;
        if (m < M) {
          float v = acc[i][j][reg] + bn;
          if (relu) v = fmaxf(v, 0.f);
          C[(size_t)m * N + n] = f2bf(v);
        }
      }
    }
  }
}

// ---------------------------------------------------------------------------
// Persistent cooperative GRU scan: one launch per 61-step chunk.
// Grid 256 wgs x 256 thr; wg owns NJ=8 j-columns x 3 gates. Weights staged
// into LDS ONCE per chunk (24 real rows + 8 zero rows = 2 MFMA n-tiles of 16).
// Per step: A-frags read h ping-pong directly from global (L2-resident);
// MFMA -> hg LDS scratch -> gate math (fp32 h in registers) -> grid.sync().
// ---------------------------------------------------------------------------
#define NJ  8
#define KLD 2056   // padded K stride: 16B-aligned rows, <=2-way LDS conflicts

namespace cg = cooperative_groups;

__global__ void gru_scan(
    bf16_t* __restrict__ hb0, bf16_t* __restrict__ hb1, int pp0,
    float* __restrict__ h_f,
    const bf16_t* __restrict__ Whh_bf, const bf16_t* __restrict__ xg_c,
    const float* __restrict__ b_hh, bf16_t* __restrict__ hs_c)
{
  extern __shared__ char dyn_lds[];
  bf16_t* wst = (bf16_t*)dyn_lds;                       // 32 x KLD bf16
  float*  hgs = (float*)(dyn_lds + 32 * KLD * 2);       // 32 x 65 fp32

  const int tid  = threadIdx.x;
  const int wave = tid >> 6;
  const int lane = tid & 63;
  const int l16  = lane & 15;
  const int quad = lane >> 4;
  const int j0   = blockIdx.x * NJ;

  // ---- stage weights once: row r<24: gate r>>3, j = j0 + (r&7); rows 24..31 zero
  for (int i = tid; i < 24 * 256; i += 256) {
    const int r  = i >> 8;
    const int c8 = (i & 255) << 3;
    const int g  = r >> 3, jr = r & 7;
    const uint4 v = *(const uint4*)(Whh_bf + ((size_t)(g * HM_ + j0 + jr)) * HM_ + c8);
    *(uint4*)&wst[r * KLD + c8] = v;
  }
  for (int i = tid; i < 8 * 256; i += 256) {
    const int r  = 24 + (i >> 8);
    const int c8 = (i & 255) << 3;
    uint4 z = {0u, 0u, 0u, 0u};
    *(uint4*)&wst[r * KLD + c8] = z;
  }

  // gate-thread ownership: j = tid&7 (fixed), b in {tid>>3, 32+tid>>3}
  const int gj  = tid & 7;
  const int gb0 = tid >> 3;
  const float bhr = b_hh[j0 + gj];
  const float bhz = b_hh[HM_ + j0 + gj];
  const float bhn = b_hh[2 * HM_ + j0 + gj];
  float hreg0 = h_f[(size_t)gb0 * HM_ + j0 + gj];
  float hreg1 = h_f[(size_t)(gb0 + 32) * HM_ + j0 + gj];

  cg::grid_group grid = cg::this_grid();
  __syncthreads();  // wst ready (block-local)

  int cur = pp0;
  for (int tt = 0; tt < TC_; ++tt) {
    const bf16_t* hin = cur ? hb1 : hb0;
    bf16_t* hout      = cur ? hb0 : hb1;

    f32x4 acc0 = {0.f, 0.f, 0.f, 0.f};
    f32x4 acc1 = {0.f, 0.f, 0.f, 0.f};
    const bf16_t* hrow = hin + (size_t)(wave * 16 + l16) * HM_ + quad * 8;
    #pragma unroll 4
    for (int k0 = 0; k0 < HM_; k0 += 32) {
      const bf16x8 af = *(const bf16x8*)(hrow + k0);
      const bf16x8 b0 = *(const bf16x8*)&wst[l16 * KLD + k0 + quad * 8];
      const bf16x8 b1 = *(const bf16x8*)&wst[(16 + l16) * KLD + k0 + quad * 8];
      acc0 = __builtin_amdgcn_mfma_f32_16x16x32_bf16(af, b0, acc0, 0, 0, 0);
      acc1 = __builtin_amdgcn_mfma_f32_16x16x32_bf16(af, b1, acc1, 0, 0, 0);
    }
    // dump hg to LDS scratch: row = n-row (gate*8+j), col = batch
    #pragma unroll
    for (int reg = 0; reg < 4; ++reg) {
      const int b = wave * 16 + quad * 4 + reg;
      hgs[l16 * 65 + b] = acc0[reg];
      if (l16 < 8) hgs[(16 + l16) * 65 + b] = acc1[reg];
    }
    __syncthreads();
    // gate math: 2 (b,j) outputs per thread
    #pragma unroll
    for (int rep = 0; rep < 2; ++rep) {
      const int b = gb0 + rep * 32;
      float& hreg = rep ? hreg1 : hreg0;
      const size_t xrow = (size_t)(b * TC_ + tt) * G3_ + j0 + gj;
      const float xr = bf2f(xg_c[xrow]);
      const float xz = bf2f(xg_c[xrow + HM_]);
      const float xn = bf2f(xg_c[xrow + 2 * HM_]);
      const float hr = hgs[gj * 65 + b];
      const float hz = hgs[(8 + gj) * 65 + b];
      const float hn = hgs[(16 + gj) * 65 + b];
      const float r = 1.f / (1.f + expf(-(xr + hr + bhr)));
      const float z = 1.f / (1.f + expf(-(xz + hz + bhz)));
      const float n = tanhf(xn + r * (hn + bhn));
      const float hnew = (1.f - z) * n + z * hreg;
      hreg = hnew;
      const bf16_t hb = f2bf(hnew);
      hout[(size_t)b * HM_ + j0 + gj] = hb;
      hs_c[(size_t)(b * TC_ + tt) * HM_ + j0 + gj] = hb;
    }
    __threadfence();
    grid.sync();
    cur ^= 1;
  }
  // persist fp32 h master for next chunk
  h_f[(size_t)gb0 * HM_ + j0 + gj]        = hreg0;
  h_f[(size_t)(gb0 + 32) * HM_ + j0 + gj] = hreg1;
}

// ---------------------------------------------------------------------------
// L1 GEMM with gathered rows (K=24, fp32 vector), bf16 output. (unchanged)
// ---------------------------------------------------------------------------
#define BM 64
#define BN 64
#define BKK 16

__global__ __launch_bounds__(256) void gemm_l1_gather(
    const float* __restrict__ x, const float* __restrict__ W,
    const float* __restrict__ bias, bf16_t* __restrict__ C, int t0)
{
  __shared__ float As[BKK][BM];
  __shared__ float Ws[BKK][BN];
  const int tid = threadIdx.x;
  const int m0 = blockIdx.x * BM;
  const int n0 = blockIdx.y * BN;
  const int lr = tid >> 2;
  const int kq = (tid & 3) << 2;
  const int ty = tid >> 4;
  const int tx = tid & 15;
  const int r = m0 + lr;
  const int b = r / TC_;
  const int tt = r - b * TC_;
  const size_t srow = (size_t)b * T_ + t0 + tt;
  float acc[4][4] = {};
  for (int k0 = 0; k0 < IN_; k0 += BKK) {
    {
      float v0 = 0.f, v1 = 0.f, v2 = 0.f, v3 = 0.f;
      const int kk = k0 + kq;
      const float* src = x + srow * IN_ + kk;
      if (kk + 4 <= IN_) {
        const float4 v = *(const float4*)src;
        v0 = v.x; v1 = v.y; v2 = v.z; v3 = v.w;
      }
      As[kq + 0][lr] = v0; As[kq + 1][lr] = v1;
      As[kq + 2][lr] = v2; As[kq + 3][lr] = v3;
      float w0 = 0.f, w1 = 0.f, w2 = 0.f, w3 = 0.f;
      const float* srcw = W + (size_t)(n0 + lr) * IN_ + kk;
      if (kk + 4 <= IN_) {
        const float4 w = *(const float4*)srcw;
        w0 = w.x; w1 = w.y; w2 = w.z; w3 = w.w;
      }
      Ws[kq + 0][lr] = w0; Ws[kq + 1][lr] = w1;
      Ws[kq + 2][lr] = w2; Ws[kq + 3][lr] = w3;
    }
    __syncthreads();
    #pragma unroll
    for (int k = 0; k < BKK; ++k) {
      const float4 av = *(const float4*)&As[k][ty << 2];
      const float4 bv = *(const float4*)&Ws[k][tx << 2];
      const float aa[4] = {av.x, av.y, av.z, av.w};
      const float bb[4] = {bv.x, bv.y, bv.z, bv.w};
      #pragma unroll
      for (int i = 0; i < 4; ++i)
        #pragma unroll
        for (int j = 0; j < 4; ++j)
          acc[i][j] = fmaf(aa[i], bb[j], acc[i][j]);
    }
    __syncthreads();
  }
  const float4 bvec = *(const float4*)&bias[n0 + (tx << 2)];
  const float bb[4] = {bvec.x, bvec.y, bvec.z, bvec.w};
  #pragma unroll
  for (int i = 0; i < 4; ++i) {
    ushort4_t ov;
    ov.x = f2bf(fmaxf(acc[i][0] + bb[0], 0.f));
    ov.y = f2bf(fmaxf(acc[i][1] + bb[1], 0.f));
    ov.z = f2bf(fmaxf(acc[i][2] + bb[2], 0.f));
    ov.w = f2bf(fmaxf(acc[i][3] + bb[3], 0.f));
    *(ushort4_t*)&C[(size_t)(m0 + (ty << 2) + i) * H1_ + n0 + (tx << 2)] = ov;
  }
}

// Heads for one chunk (outs bf16). (unchanged)
__global__ __launch_bounds__(256) void heads_kernel(
    const bf16_t* __restrict__ outs_c, const int* __restrict__ label,
    const float* __restrict__ W4, const float* __restrict__ b4,
    const float* __restrict__ W5, const float* __restrict__ b5,
    const float* __restrict__ W6, const float* __restrict__ b6,
    float* __restrict__ out, int t0)
{
  const int r = blockIdx.x;
  const int b = r / TC_;
  const int tt = r - b * TC_;
  int lab = label[b];
  lab = lab < 0 ? 0 : (lab > C_ - 1 ? C_ - 1 : lab);
  const int tid = threadIdx.x;
  const bf16_t* o = outs_c + (size_t)r * PEN_;
  const float* w4 = W4 + (size_t)lab * PEN_;
  const float* w5 = W5 + (size_t)lab * PEN_;
  const float* w6 = W6 + (size_t)lab * PEN_;
  float s4 = 0.f, s5 = 0.f, s6 = 0.f;
  for (int p = tid; p < PEN_; p += 256) {
    const float ov = bf2f(o[p]);
    s4 = fmaf(ov, w4[p], s4);
    s5 = fmaf(ov, w5[p], s5);
    s6 = fmaf(ov, w6[p], s6);
  }
  #pragma unroll
  for (int off = 32; off > 0; off >>= 1) {
    s4 += __shfl_down(s4, off, 64);
    s5 += __shfl_down(s5, off, 64);
    s6 += __shfl_down(s6, off, 64);
  }
  __shared__ float red[4][3];
  const int wave = tid >> 6;
  if ((tid & 63) == 0) { red[wave][0] = s4; red[wave][1] = s5; red[wave][2] = s6; }
  __syncthreads();
  if (tid == 0) {
    const int bt = b * T_ + t0 + tt;
    out[bt]           = red[0][0] + red[1][0] + red[2][0] + red[3][0] + b4[lab];
    out[BT_ + bt]     = red[0][1] + red[1][1] + red[2][1] + red[3][1] + b5[lab];
    out[2 * BT_ + bt] = red[0][2] + red[1][2] + red[2][2] + red[3][2] + b6[lab];
    if (t0 == 0 && r == 0) { out[3 * BT_] = 0.f; out[3 * BT_ + 1] = 0.f; }
  }
}

__global__ __launch_bounds__(256) void cvt_bf(const float* __restrict__ src,
                                              bf16_t* __restrict__ dst, int n) {
  const int i = (blockIdx.x * 256 + threadIdx.x) * 4;
  if (i + 4 <= n) {
    const float4 v = *(const float4*)&src[i];
    ushort4_t o = {f2bf(v.x), f2bf(v.y), f2bf(v.z), f2bf(v.w)};
    *(ushort4_t*)&dst[i] = o;
  }
}

__global__ __launch_bounds__(256) void zero_h(float* __restrict__ hf,
                                              bf16_t* __restrict__ hb0,
                                              bf16_t* __restrict__ hb1) {
  const int i = blockIdx.x * 256 + threadIdx.x;  // 131072
  hf[i] = 0.f; hb0[i] = 0; hb1[i] = 0;
}

extern "C" void kernel_launch(void* const* d_in, const int* in_sizes, int n_in,
                              void* d_out, int out_size, void* d_ws, size_t ws_size,
                              hipStream_t stream) {
  const float* x     = (const float*)d_in[0];
  const int*   label = (const int*)d_in[1];
  const float* W1    = (const float*)d_in[2];
  const float* b1    = (const float*)d_in[3];
  const float* W2    = (const float*)d_in[4];
  const float* b2    = (const float*)d_in[5];
  const float* W_ih  = (const float*)d_in[6];
  const float* W_hh  = (const float*)d_in[7];
  const float* b_ih  = (const float*)d_in[8];
  const float* b_hh  = (const float*)d_in[9];
  const float* W3    = (const float*)d_in[10];
  const float* b3    = (const float*)d_in[11];
  const float* W4    = (const float*)d_in[12];
  const float* b4    = (const float*)d_in[13];
  const float* W5    = (const float*)d_in[14];
  const float* b5    = (const float*)d_in[15];
  const float* W6    = (const float*)d_in[16];
  const float* b6    = (const float*)d_in[17];

  // Workspace layout (bytes), total 98,172,928 — proven to fit in R4/R5.
  const size_t NEEDED = 98172928UL;
  if (ws_size < NEEDED) return;

  char* ws = (char*)d_ws;
  bf16_t* xg_c   = (bf16_t*)(ws + 0);
  bf16_t* out2_c = (bf16_t*)(ws + 47972352UL);
  bf16_t* hs_c   = out2_c;
  bf16_t* out1_c = (bf16_t*)(ws + 63963136UL);
  bf16_t* outs_c = out1_c;
  bf16_t* Whh_bf = (bf16_t*)(ws + 71958528UL);
  float*  h_f    = (float*)(ws + 97124352UL);
  bf16_t* hbuf0  = (bf16_t*)(ws + 97648640UL);
  bf16_t* hbuf1  = (bf16_t*)(ws + 97910784UL);
  float* out = (float*)d_out;

  const dim3 blk(256);

  cvt_bf<<<dim3(G3_ * HM_ / 1024), blk, 0, stream>>>(W_hh, Whh_bf, G3_ * HM_);
  zero_h<<<dim3(B_ * HM_ / 256), blk, 0, stream>>>(h_f, hbuf0, hbuf1);

  const unsigned scan_lds = 32 * KLD * 2 + 32 * 65 * 4;
  int pp = 0;
  for (int c = 0; c < NCH; ++c) {
    const int t0 = c * TC_;
    gemm_l1_gather<<<dim3(MC / BM, H1_ / BN), blk, 0, stream>>>(x, W1, b1, out1_c, t0);
    gemm_mfma<<<dim3((MC + GBM - 1) / GBM, H2_ / GBN), blk, 0, stream>>>(
        out1_c, W2, b2, out2_c, MC, H2_, H1_, 1);
    gemm_mfma<<<dim3((MC + GBM - 1) / GBM, G3_ / GBN), blk, 0, stream>>>(
        out2_c, W_ih, b_ih, xg_c, MC, G3_, H2_, 0);

    {
      bf16_t* a0 = hbuf0; bf16_t* a1 = hbuf1; int app = pp;
      float* ahf = h_f; const bf16_t* awh = Whh_bf; const bf16_t* axg = xg_c;
      const float* abh = b_hh; bf16_t* ahs = hs_c;
      void* args[8] = {&a0, &a1, &app, &ahf, &awh, &axg, &abh, &ahs};
      hipLaunchCooperativeKernel((void*)gru_scan, dim3(HM_ / NJ), blk, args,
                                 scan_lds, stream);
    }
    pp ^= 1;  // TC_=61 odd -> parity flips per chunk

    gemm_mfma<<<dim3((MC + GBM - 1) / GBM, PEN_ / GBN), blk, 0, stream>>>(
        hs_c, W3, b3, outs_c, MC, PEN_, HM_, 1);
    heads_kernel<<<dim3(MC), blk, 0, stream>>>(
        outs_c, label, W4, b4, W5, b5, W6, b6, out, t0);
  }
}

// Round 8
// 9399.174 us; speedup vs baseline: 3.0162x; 3.0162x over previous
//
#include <hip/hip_runtime.h>
#include <math.h>

#define B_   64
#define T_   366
#define IN_  24
#define H1_  1024
#define H2_  2048
#define HM_  2048
#define G3_  (3 * HM_)
#define PEN_ 1024
#define C_   21
#define BT_  (B_ * T_)

#define TC_  61              // T-chunk length (366 = 6*61)
#define NCH  6
#define MC   (B_ * TC_)      // 3904 rows per chunk

typedef unsigned short bf16_t;
typedef __bf16 bf16x8 __attribute__((ext_vector_type(8)));
typedef float  f32x4  __attribute__((ext_vector_type(4)));

__device__ __forceinline__ float bf2f(bf16_t u) {
  return __uint_as_float(((unsigned int)u) << 16);
}
__device__ __forceinline__ bf16_t f2bf(float f) {
  unsigned int x = __float_as_uint(f);
  unsigned int r = (x + 0x7fffu + ((x >> 16) & 1u)) >> 16;
  return (bf16_t)r;
}

struct ushort4_t { bf16_t x, y, z, w; };

// ---------------------------------------------------------------------------
// MFMA bf16 GEMM (verified R5-R7 incl. post-timing in R5): C = act(A@W^T+b).
// ---------------------------------------------------------------------------
#define GBM 128
#define GBN 128
#define GBK 32
#define LDT 40

__global__ __launch_bounds__(256) void gemm_mfma(
    const bf16_t* __restrict__ A, const float* __restrict__ W,
    const float* __restrict__ bias, bf16_t* __restrict__ C,
    int M, int N, int K, int relu)
{
  __shared__ bf16_t Asl[GBM * LDT];
  __shared__ bf16_t Wsl[GBN * LDT];
  const int tid  = threadIdx.x;
  const int m0   = blockIdx.x * GBM;
  const int n0   = blockIdx.y * GBN;
  const int wave = tid >> 6;
  const int lane = tid & 63;
  const int l16  = lane & 15;
  const int quad = lane >> 4;
  const int wm   = (wave & 1) * 64;
  const int wn   = (wave >> 1) * 64;
  const int srow = tid >> 1;
  const int sseg = (tid & 1) << 4;
  const int arow = (m0 + srow < M) ? (m0 + srow) : (M - 1);

  f32x4 acc[4][4];
  #pragma unroll
  for (int i = 0; i < 4; ++i)
    #pragma unroll
    for (int j = 0; j < 4; ++j)
      acc[i][j] = (f32x4){0.f, 0.f, 0.f, 0.f};

  for (int k0 = 0; k0 < K; k0 += GBK) {
    {
      const bf16_t* ga = A + (size_t)arow * K + k0 + sseg;
      const uint4 a0 = *(const uint4*)ga;
      const uint4 a1 = *(const uint4*)(ga + 8);
      *(uint4*)&Asl[srow * LDT + sseg]     = a0;
      *(uint4*)&Asl[srow * LDT + sseg + 8] = a1;
      const float* gw = W + (size_t)(n0 + srow) * K + k0 + sseg;
      const float4 w0 = *(const float4*)gw;
      const float4 w1 = *(const float4*)(gw + 4);
      const float4 w2 = *(const float4*)(gw + 8);
      const float4 w3 = *(const float4*)(gw + 12);
      ushort4_t p0 = {f2bf(w0.x), f2bf(w0.y), f2bf(w0.z), f2bf(w0.w)};
      ushort4_t p1 = {f2bf(w1.x), f2bf(w1.y), f2bf(w1.z), f2bf(w1.w)};
      ushort4_t p2 = {f2bf(w2.x), f2bf(w2.y), f2bf(w2.z), f2bf(w2.w)};
      ushort4_t p3 = {f2bf(w3.x), f2bf(w3.y), f2bf(w3.z), f2bf(w3.w)};
      *(ushort4_t*)&Wsl[srow * LDT + sseg]      = p0;
      *(ushort4_t*)&Wsl[srow * LDT + sseg + 4]  = p1;
      *(ushort4_t*)&Wsl[srow * LDT + sseg + 8]  = p2;
      *(ushort4_t*)&Wsl[srow * LDT + sseg + 12] = p3;
    }
    __syncthreads();
    bf16x8 af[4], bf[4];
    #pragma unroll
    for (int i = 0; i < 4; ++i)
      af[i] = *(const bf16x8*)&Asl[(wm + 16 * i + l16) * LDT + quad * 8];
    #pragma unroll
    for (int j = 0; j < 4; ++j)
      bf[j] = *(const bf16x8*)&Wsl[(wn + 16 * j + l16) * LDT + quad * 8];
    #pragma unroll
    for (int i = 0; i < 4; ++i)
      #pragma unroll
      for (int j = 0; j < 4; ++j)
        acc[i][j] = __builtin_amdgcn_mfma_f32_16x16x32_bf16(af[i], bf[j], acc[i][j], 0, 0, 0);
    __syncthreads();
  }

  #pragma unroll
  for (int j = 0; j < 4; ++j) {
    const int n = n0 + wn + 16 * j + l16;
    const float bn = bias[n];
    #pragma unroll
    for (int i = 0; i < 4; ++i) {
      #pragma unroll
      for (int reg = 0; reg < 4; ++reg) {
        const int m = m0 + wm + 16 * i + quad * 4 + reg;
        if (m < M) {
          float v = acc[i][j][reg] + bn;
          if (relu) v = fmaxf(v, 0.f);
          C[(size_t)m * N + n] = f2bf(v);
        }
      }
    }
  }
}

// ---------------------------------------------------------------------------
// GRU step — R5-proven structure (128 wgs x 256 thr, wg owns 16 j x 3 gates,
// static 16KB LDS, gate math in MFMA lanes, late h_f read) + ONE change:
// register double-buffering of the staging loads (next k-tile's global loads
// issued between the barriers so their latency overlaps MFMA+frag reads).
// ---------------------------------------------------------------------------
#define HLD 72   // padded LDS stride for 64-k tiles (R5 value)

__global__ __launch_bounds__(256) void gru_step(
    const bf16_t* __restrict__ h_bf_in, float* __restrict__ h_f,
    const bf16_t* __restrict__ Whh_bf, const bf16_t* __restrict__ xg_c,
    const float* __restrict__ b_hh,
    bf16_t* __restrict__ h_bf_out, bf16_t* __restrict__ hs_c, int tt)
{
  __shared__ bf16_t hst[64 * HLD];
  __shared__ bf16_t wst[48 * HLD];
  const int tid  = threadIdx.x;
  const int wave = tid >> 6;
  const int lane = tid & 63;
  const int l16  = lane & 15;
  const int quad = lane >> 4;
  const int j0   = blockIdx.x * 16;

  f32x4 acc[3];
  acc[0] = (f32x4){0.f, 0.f, 0.f, 0.f};
  acc[1] = acc[0];
  acc[2] = acc[0];

  const int hrow = tid >> 2;          // 0..63
  const int hseg = (tid & 3) << 4;    // 0,16,32,48
  const int wg   = hrow >> 4;         // gate index (valid for tid<192)
  const int wjr  = hrow & 15;

  const bf16_t* gh_base = h_bf_in + (size_t)hrow * HM_ + hseg;
  const bf16_t* gw_base = Whh_bf + (size_t)(wg * HM_ + j0 + wjr) * HM_ + hseg;

  // preload k-tile 0 into registers
  uint4 h0 = *(const uint4*)(gh_base);
  uint4 h1 = *(const uint4*)(gh_base + 8);
  uint4 w0 = {0u,0u,0u,0u}, w1 = {0u,0u,0u,0u};
  if (tid < 192) { w0 = *(const uint4*)(gw_base); w1 = *(const uint4*)(gw_base + 8); }

  for (int k0 = 0; k0 < HM_; k0 += 64) {
    // regs -> LDS
    *(uint4*)&hst[hrow * HLD + hseg]     = h0;
    *(uint4*)&hst[hrow * HLD + hseg + 8] = h1;
    if (tid < 192) {
      *(uint4*)&wst[hrow * HLD + hseg]     = w0;
      *(uint4*)&wst[hrow * HLD + hseg + 8] = w1;
    }
    __syncthreads();
    // prefetch next k-tile (latency overlaps MFMA below)
    if (k0 + 64 < HM_) {
      h0 = *(const uint4*)(gh_base + k0 + 64);
      h1 = *(const uint4*)(gh_base + k0 + 64 + 8);
      if (tid < 192) {
        w0 = *(const uint4*)(gw_base + k0 + 64);
        w1 = *(const uint4*)(gw_base + k0 + 64 + 8);
      }
    }
    #pragma unroll
    for (int s = 0; s < 2; ++s) {
      const bf16x8 afr = *(const bf16x8*)&hst[(wave * 16 + l16) * HLD + s * 32 + quad * 8];
      #pragma unroll
      for (int g = 0; g < 3; ++g) {
        const bf16x8 bfr = *(const bf16x8*)&wst[(g * 16 + l16) * HLD + s * 32 + quad * 8];
        acc[g] = __builtin_amdgcn_mfma_f32_16x16x32_bf16(afr, bfr, acc[g], 0, 0, 0);
      }
    }
    __syncthreads();
  }

  // epilogue — R5 verbatim (late h_f read, gate math in MFMA lanes)
  const int j = j0 + l16;
  const float bh_r = b_hh[j];
  const float bh_z = b_hh[HM_ + j];
  const float bh_n = b_hh[2 * HM_ + j];
  #pragma unroll
  for (int reg = 0; reg < 4; ++reg) {
    const int b = wave * 16 + quad * 4 + reg;
    const size_t xrow = (size_t)(b * TC_ + tt) * G3_;
    const float xr = bf2f(xg_c[xrow + j]);
    const float xz = bf2f(xg_c[xrow + HM_ + j]);
    const float xn = bf2f(xg_c[xrow + 2 * HM_ + j]);
    const float r = 1.f / (1.f + expf(-(xr + acc[0][reg] + bh_r)));
    const float z = 1.f / (1.f + expf(-(xz + acc[1][reg] + bh_z)));
    const float n = tanhf(xn + r * (acc[2][reg] + bh_n));
    const float hp = h_f[b * HM_ + j];
    const float hnew = (1.f - z) * n + z * hp;
    h_f[b * HM_ + j] = hnew;
    const bf16_t hb = f2bf(hnew);
    h_bf_out[b * HM_ + j] = hb;
    hs_c[(size_t)(b * TC_ + tt) * HM_ + j] = hb;
  }
}

// ---------------------------------------------------------------------------
// L1 GEMM with gathered rows (K=24, fp32 vector), bf16 output. (R5-proven)
// ---------------------------------------------------------------------------
#define BM 64
#define BN 64
#define BKK 16

__global__ __launch_bounds__(256) void gemm_l1_gather(
    const float* __restrict__ x, const float* __restrict__ W,
    const float* __restrict__ bias, bf16_t* __restrict__ C, int t0)
{
  __shared__ float As[BKK][BM];
  __shared__ float Ws[BKK][BN];
  const int tid = threadIdx.x;
  const int m0 = blockIdx.x * BM;
  const int n0 = blockIdx.y * BN;
  const int lr = tid >> 2;
  const int kq = (tid & 3) << 2;
  const int ty = tid >> 4;
  const int tx = tid & 15;
  const int r = m0 + lr;
  const int b = r / TC_;
  const int tt = r - b * TC_;
  const size_t srow = (size_t)b * T_ + t0 + tt;
  float acc[4][4] = {};
  for (int k0 = 0; k0 < IN_; k0 += BKK) {
    {
      float v0 = 0.f, v1 = 0.f, v2 = 0.f, v3 = 0.f;
      const int kk = k0 + kq;
      const float* src = x + srow * IN_ + kk;
      if (kk + 4 <= IN_) {
        const float4 v = *(const float4*)src;
        v0 = v.x; v1 = v.y; v2 = v.z; v3 = v.w;
      }
      As[kq + 0][lr] = v0; As[kq + 1][lr] = v1;
      As[kq + 2][lr] = v2; As[kq + 3][lr] = v3;
      float w0 = 0.f, w1 = 0.f, w2 = 0.f, w3 = 0.f;
      const float* srcw = W + (size_t)(n0 + lr) * IN_ + kk;
      if (kk + 4 <= IN_) {
        const float4 w = *(const float4*)srcw;
        w0 = w.x; w1 = w.y; w2 = w.z; w3 = w.w;
      }
      Ws[kq + 0][lr] = w0; Ws[kq + 1][lr] = w1;
      Ws[kq + 2][lr] = w2; Ws[kq + 3][lr] = w3;
    }
    __syncthreads();
    #pragma unroll
    for (int k = 0; k < BKK; ++k) {
      const float4 av = *(const float4*)&As[k][ty << 2];
      const float4 bv = *(const float4*)&Ws[k][tx << 2];
      const float aa[4] = {av.x, av.y, av.z, av.w};
      const float bb[4] = {bv.x, bv.y, bv.z, bv.w};
      #pragma unroll
      for (int i = 0; i < 4; ++i)
        #pragma unroll
        for (int j = 0; j < 4; ++j)
          acc[i][j] = fmaf(aa[i], bb[j], acc[i][j]);
    }
    __syncthreads();
  }
  const float4 bvec = *(const float4*)&bias[n0 + (tx << 2)];
  const float bb[4] = {bvec.x, bvec.y, bvec.z, bvec.w};
  #pragma unroll
  for (int i = 0; i < 4; ++i) {
    ushort4_t ov;
    ov.x = f2bf(fmaxf(acc[i][0] + bb[0], 0.f));
    ov.y = f2bf(fmaxf(acc[i][1] + bb[1], 0.f));
    ov.z = f2bf(fmaxf(acc[i][2] + bb[2], 0.f));
    ov.w = f2bf(fmaxf(acc[i][3] + bb[3], 0.f));
    *(ushort4_t*)&C[(size_t)(m0 + (ty << 2) + i) * H1_ + n0 + (tx << 2)] = ov;
  }
}

// Heads for one chunk (outs bf16). (R5-proven)
__global__ __launch_bounds__(256) void heads_kernel(
    const bf16_t* __restrict__ outs_c, const int* __restrict__ label,
    const float* __restrict__ W4, const float* __restrict__ b4,
    const float* __restrict__ W5, const float* __restrict__ b5,
    const float* __restrict__ W6, const float* __restrict__ b6,
    float* __restrict__ out, int t0)
{
  const int r = blockIdx.x;
  const int b = r / TC_;
  const int tt = r - b * TC_;
  int lab = label[b];
  lab = lab < 0 ? 0 : (lab > C_ - 1 ? C_ - 1 : lab);
  const int tid = threadIdx.x;
  const bf16_t* o = outs_c + (size_t)r * PEN_;
  const float* w4 = W4 + (size_t)lab * PEN_;
  const float* w5 = W5 + (size_t)lab * PEN_;
  const float* w6 = W6 + (size_t)lab * PEN_;
  float s4 = 0.f, s5 = 0.f, s6 = 0.f;
  for (int p = tid; p < PEN_; p += 256) {
    const float ov = bf2f(o[p]);
    s4 = fmaf(ov, w4[p], s4);
    s5 = fmaf(ov, w5[p], s5);
    s6 = fmaf(ov, w6[p], s6);
  }
  #pragma unroll
  for (int off = 32; off > 0; off >>= 1) {
    s4 += __shfl_down(s4, off, 64);
    s5 += __shfl_down(s5, off, 64);
    s6 += __shfl_down(s6, off, 64);
  }
  __shared__ float red[4][3];
  const int wave = tid >> 6;
  if ((tid & 63) == 0) { red[wave][0] = s4; red[wave][1] = s5; red[wave][2] = s6; }
  __syncthreads();
  if (tid == 0) {
    const int bt = b * T_ + t0 + tt;
    out[bt]           = red[0][0] + red[1][0] + red[2][0] + red[3][0] + b4[lab];
    out[BT_ + bt]     = red[0][1] + red[1][1] + red[2][1] + red[3][1] + b5[lab];
    out[2 * BT_ + bt] = red[0][2] + red[1][2] + red[2][2] + red[3][2] + b6[lab];
    if (t0 == 0 && r == 0) { out[3 * BT_] = 0.f; out[3 * BT_ + 1] = 0.f; }
  }
}

__global__ __launch_bounds__(256) void cvt_bf(const float* __restrict__ src,
                                              bf16_t* __restrict__ dst, int n) {
  const int i = (blockIdx.x * 256 + threadIdx.x) * 4;
  if (i + 4 <= n) {
    const float4 v = *(const float4*)&src[i];
    ushort4_t o = {f2bf(v.x), f2bf(v.y), f2bf(v.z), f2bf(v.w)};
    *(ushort4_t*)&dst[i] = o;
  }
}

__global__ __launch_bounds__(256) void zero_h(float* __restrict__ hf,
                                              bf16_t* __restrict__ hb0,
                                              bf16_t* __restrict__ hb1) {
  const int i = blockIdx.x * 256 + threadIdx.x;  // 131072
  hf[i] = 0.f; hb0[i] = 0; hb1[i] = 0;
}

extern "C" void kernel_launch(void* const* d_in, const int* in_sizes, int n_in,
                              void* d_out, int out_size, void* d_ws, size_t ws_size,
                              hipStream_t stream) {
  const float* x     = (const float*)d_in[0];
  const int*   label = (const int*)d_in[1];
  const float* W1    = (const float*)d_in[2];
  const float* b1    = (const float*)d_in[3];
  const float* W2    = (const float*)d_in[4];
  const float* b2    = (const float*)d_in[5];
  const float* W_ih  = (const float*)d_in[6];
  const float* W_hh  = (const float*)d_in[7];
  const float* b_ih  = (const float*)d_in[8];
  const float* b_hh  = (const float*)d_in[9];
  const float* W3    = (const float*)d_in[10];
  const float* b3    = (const float*)d_in[11];
  const float* W4    = (const float*)d_in[12];
  const float* b4    = (const float*)d_in[13];
  const float* W5    = (const float*)d_in[14];
  const float* b5    = (const float*)d_in[15];
  const float* W6    = (const float*)d_in[16];
  const float* b6    = (const float*)d_in[17];

  // Workspace layout (bytes), total 98,172,928 — proven R4-R7.
  const size_t NEEDED = 98172928UL;
  if (ws_size < NEEDED) return;

  char* ws = (char*)d_ws;
  bf16_t* xg_c   = (bf16_t*)(ws + 0);
  bf16_t* out2_c = (bf16_t*)(ws + 47972352UL);
  bf16_t* hs_c   = out2_c;
  bf16_t* out1_c = (bf16_t*)(ws + 63963136UL);
  bf16_t* outs_c = out1_c;
  bf16_t* Whh_bf = (bf16_t*)(ws + 71958528UL);
  float*  h_f    = (float*)(ws + 97124352UL);
  bf16_t* hbuf[2];
  hbuf[0] = (bf16_t*)(ws + 97648640UL);
  hbuf[1] = (bf16_t*)(ws + 97910784UL);
  float* out = (float*)d_out;

  const dim3 blk(256);

  cvt_bf<<<dim3(G3_ * HM_ / 1024), blk, 0, stream>>>(W_hh, Whh_bf, G3_ * HM_);
  zero_h<<<dim3(B_ * HM_ / 256), blk, 0, stream>>>(h_f, hbuf[0], hbuf[1]);

  int pp = 0;
  for (int c = 0; c < NCH; ++c) {
    const int t0 = c * TC_;
    gemm_l1_gather<<<dim3(MC / BM, H1_ / BN), blk, 0, stream>>>(x, W1, b1, out1_c, t0);
    gemm_mfma<<<dim3((MC + GBM - 1) / GBM, H2_ / GBN), blk, 0, stream>>>(
        out1_c, W2, b2, out2_c, MC, H2_, H1_, 1);
    gemm_mfma<<<dim3((MC + GBM - 1) / GBM, G3_ / GBN), blk, 0, stream>>>(
        out2_c, W_ih, b_ih, xg_c, MC, G3_, H2_, 0);

    for (int tt = 0; tt < TC_; ++tt) {
      gru_step<<<dim3(HM_ / 16), blk, 0, stream>>>(
          hbuf[pp], h_f, Whh_bf, xg_c, b_hh, hbuf[1 - pp], hs_c, tt);
      pp ^= 1;
    }

    gemm_mfma<<<dim3((MC + GBM - 1) / GBM, PEN_ / GBN), blk, 0, stream>>>(
        hs_c, W3, b3, outs_c, MC, PEN_, HM_, 1);
    heads_kernel<<<dim3(MC), blk, 0, stream>>>(
        outs_c, label, W4, b4, W5, b5, W6, b6, out, t0);
  }
}